// Round 19
// baseline (397.474 us; speedup 1.0000x reference)
//
#include <hip/hip_runtime.h>
#include <cstdint>
#include <cstddef>

#define NBATCH 128
#define NCH    256
#define NHW    1024
#define NTIME  64
#define NCLS   128

typedef _Float16 f16_t;
typedef _Float16 f16x8 __attribute__((ext_vector_type(8)));
typedef _Float16 half2_t __attribute__((ext_vector_type(2)));
typedef short bf16x8 __attribute__((ext_vector_type(8)));
typedef short bf16x4 __attribute__((ext_vector_type(4)));
typedef float f32x4 __attribute__((ext_vector_type(4)));
typedef unsigned short ushort_t;

#if defined(__has_builtin)
#  if __has_builtin(__builtin_amdgcn_fdot2)
#    define HAS_FDOT2 1
#  endif
#endif
#ifndef HAS_FDOT2
#  define HAS_FDOT2 0
#endif

__device__ __forceinline__ float dot2acc(half2_t a, half2_t b, float c){
#if HAS_FDOT2
  return __builtin_amdgcn_fdot2(a, b, c, false);
#else
  return c + (float)a.x*(float)b.x + (float)a.y*(float)b.y;
#endif
}
__device__ __forceinline__ half2_t pack2(float x, float y){
  half2_t p; p.x = (_Float16)x; p.y = (_Float16)y; return p;
}
#define BCH(x) __builtin_bit_cast(half2_t, (x))
__device__ __forceinline__ ushort_t f2bf(float x){
  unsigned u = __builtin_bit_cast(unsigned, x);
  unsigned r = (u + 0x7FFFu + ((u>>16)&1u)) >> 16;
  return (ushort_t)r;
}
__device__ __forceinline__ float sig_(float x){
  x = fminf(30.f, fmaxf(-30.f, x));
  return 1.f/(1.f+__expf(-x));
}
__device__ __forceinline__ float tanh_(float x){
  x = fminf(15.f, fmaxf(-15.f, x));
  float e = __expf(2.f*x);
  return (e-1.f)/(e+1.f);
}

// ---------------- K-prep: ALL weight conversions in one kernel ----------------
__global__ __launch_bounds__(256) void k_prep(
    const float* __restrict__ Wih_f, const float* __restrict__ Wih_b,
    const float* __restrict__ Wih_g, const float* __restrict__ Wgen,
    const float* __restrict__ Whh_f, const float* __restrict__ Whh_b,
    const float* __restrict__ Whh_g, const float* __restrict__ emb,
    ushort_t* __restrict__ Wf_bf, ushort_t* __restrict__ Wb_bf,
    ushort_t* __restrict__ Wg_bf, ushort_t* __restrict__ Wgen_bf,
    f16_t* __restrict__ Whf_h, f16_t* __restrict__ Whb_h, f16_t* __restrict__ Whg_h,
    ushort_t* __restrict__ emb_bf){
  int i = blockIdx.x*256 + threadIdx.x;
  if (i < 131072){ Wf_bf[i] = f2bf(Wih_f[i]); return; }
  i -= 131072;
  if (i < 131072){ Wb_bf[i] = f2bf(Wih_b[i]); return; }
  i -= 131072;
  if (i < 393216){ Wg_bf[i] = f2bf(Wih_g[i]); return; }
  i -= 393216;
  if (i < 32768){ Wgen_bf[i] = f2bf(Wgen[i]); return; }
  i -= 32768;
  if (i < 65536){ Whf_h[i] = (f16_t)Whh_f[i]; return; }
  i -= 65536;
  if (i < 65536){ Whb_h[i] = (f16_t)Whh_b[i]; return; }
  i -= 65536;
  if (i < 196608){ Whg_h[i] = (f16_t)Whh_g[i]; return; }
  i -= 196608;
  emb_bf[i] = f2bf(emb[i]);
}

// ---------------- K1: attention pooling via MFMA + fused row-sum ----------------
__global__ __launch_bounds__(256) void k_pool_mfma(const float* __restrict__ feat, const float* __restrict__ A,
    float* __restrict__ S, ushort_t* __restrict__ Cbf){
  __shared__ ushort_t As_[64*40];
  __shared__ ushort_t Fs_[128*40];
  __shared__ float sinvs[64];
  __shared__ float psum[512];
  int b = blockIdx.x >> 1, ch = blockIdx.x & 1, c0 = ch*128;
  int tid = threadIdx.x, wave = tid>>6, lane = tid&63;
  f32x4 acc[4][2] = {};
  int lr = lane & 15, lk = (lane>>4)*8;
  float sA0 = 0.f, sA1 = 0.f;
  for (int k0=0;k0<NHW;k0+=32){
    __syncthreads();
    #pragma unroll
    for (int i=0;i<2;i++){
      int c = tid + i*256, r = c>>3, kq = c&7;
      float4 v = *(const float4*)(A + ((size_t)(b*64+r))*NHW + k0 + kq*4);
      float sv = v.x+v.y+v.z+v.w;
      if (i==0) sA0 += sv; else sA1 += sv;
      bf16x4 p; p[0]=(short)f2bf(v.x); p[1]=(short)f2bf(v.y); p[2]=(short)f2bf(v.z); p[3]=(short)f2bf(v.w);
      *(bf16x4*)&As_[r*40 + kq*4] = p;
    }
    #pragma unroll
    for (int i=0;i<4;i++){
      int c = tid + i*256, r = c>>3, kq = c&7;
      float4 v = *(const float4*)(feat + ((size_t)(b*256+c0+r))*NHW + k0 + kq*4);
      bf16x4 p; p[0]=(short)f2bf(v.x); p[1]=(short)f2bf(v.y); p[2]=(short)f2bf(v.z); p[3]=(short)f2bf(v.w);
      *(bf16x4*)&Fs_[r*40 + kq*4] = p;
    }
    __syncthreads();
    bf16x8 af[4], bg[2];
    #pragma unroll
    for (int m=0;m<4;m++) af[m] = *(const bf16x8*)&As_[(m*16 + lr)*40 + lk];
    #pragma unroll
    for (int n=0;n<2;n++) bg[n] = *(const bf16x8*)&Fs_[(wave*32 + n*16 + lr)*40 + lk];
    #pragma unroll
    for (int m=0;m<4;m++)
      #pragma unroll
      for (int n=0;n<2;n++)
        acc[m][n] = __builtin_amdgcn_mfma_f32_16x16x32_bf16(af[m], bg[n], acc[m][n], 0, 0, 0);
  }
  psum[tid] = sA0;
  psum[tid+256] = sA1;
  __syncthreads();
  if (tid < 64){
    float s = 0.f;
    #pragma unroll
    for (int j=0;j<8;j++) s += psum[tid*8 + j];
    sinvs[tid] = 1.f / s;
    if (ch == 0) S[b*64 + tid] = s;
  }
  __syncthreads();
  #pragma unroll
  for (int m=0;m<4;m++)
    #pragma unroll
    for (int n=0;n<2;n++)
      #pragma unroll
      for (int j=0;j<4;j++){
        int t = m*16 + (lane>>4)*4 + j;
        int c = c0 + wave*32 + n*16 + lr;
        Cbf[((size_t)t*NBATCH + b)*NCH + c] = f2bf(acc[m][n][j] * sinvs[t]);
      }
}

// ---------------- generic bf16 MFMA GEMM ----------------
__global__ __launch_bounds__(256) void k_gemm_bf(const ushort_t* __restrict__ X, const ushort_t* __restrict__ W,
    const float* __restrict__ ba, const float* __restrict__ bb, float* __restrict__ out, int N, int K){
  __shared__ ushort_t Xs[128*40];
  __shared__ ushort_t Ws[128*40];
  int n0 = blockIdx.x*128, m0 = blockIdx.y*128;
  int tid = threadIdx.x, wave = tid>>6, lane = tid&63;
  int wr = wave>>1, wc = wave&1;
  int lr = lane & 15, lk = (lane>>4)*8;
  f32x4 acc[4][4] = {};
  for (int k0=0;k0<K;k0+=32){
    __syncthreads();
    #pragma unroll
    for (int i=0;i<2;i++){
      int c = tid + i*256, r = c>>2, kb = c&3;
      *(bf16x8*)&Xs[r*40 + kb*8] = *(const bf16x8*)(X + (size_t)(m0+r)*K + k0 + kb*8);
      *(bf16x8*)&Ws[r*40 + kb*8] = *(const bf16x8*)(W + (size_t)(n0+r)*K + k0 + kb*8);
    }
    __syncthreads();
    bf16x8 af[4], bg[4];
    #pragma unroll
    for (int m=0;m<4;m++) af[m] = *(const bf16x8*)&Xs[(wr*64 + m*16 + lr)*40 + lk];
    #pragma unroll
    for (int n=0;n<4;n++) bg[n] = *(const bf16x8*)&Ws[(wc*64 + n*16 + lr)*40 + lk];
    #pragma unroll
    for (int m=0;m<4;m++)
      #pragma unroll
      for (int n=0;n<4;n++)
        acc[m][n] = __builtin_amdgcn_mfma_f32_16x16x32_bf16(af[m], bg[n], acc[m][n], 0, 0, 0);
  }
  float bsv[4];
  #pragma unroll
  for (int n=0;n<4;n++){
    int col = n0 + wc*64 + n*16 + lr;
    bsv[n] = ba[col] + (bb ? bb[col] : 0.f);
  }
  #pragma unroll
  for (int m=0;m<4;m++)
    #pragma unroll
    for (int n=0;n<4;n++)
      #pragma unroll
      for (int j=0;j<4;j++){
        int row = m0 + wr*64 + m*16 + (lane>>4)*4 + j;
        int col = n0 + wc*64 + n*16 + lr;
        out[(size_t)row*N + col] = acc[m][n][j] + bsv[n];
      }
}

// ---------------- gx GEMM with fused xs-gather ----------------
__global__ __launch_bounds__(256) void k_gemm_gx(const ushort_t* __restrict__ Clbf,
    const ushort_t* __restrict__ emb_bf, const int* __restrict__ text,
    const ushort_t* __restrict__ W, const float* __restrict__ ba,
    float* __restrict__ out){
  __shared__ ushort_t Xs[128*40];
  __shared__ ushort_t Ws[128*40];
  __shared__ int clsL[128];
  const int N = 768, K = 512;
  int n0 = blockIdx.x*128, m0 = blockIdx.y*128;
  int tid = threadIdx.x, wave = tid>>6, lane = tid&63;
  int wr = wave>>1, wc = wave&1;
  int lr = lane & 15, lk = (lane>>4)*8;
  if (tid < 128){
    int m = m0 + tid, t = m>>7, b = m&127;
    clsL[tid] = (t==0) ? 0 : text[b*64 + (t-1)];
  }
  f32x4 acc[4][4] = {};
  __syncthreads();
  for (int k0=0;k0<K;k0+=32){
    __syncthreads();
    #pragma unroll
    for (int i=0;i<2;i++){
      int c = tid + i*256, r = c>>2, kb = c&3;
      int col = k0 + kb*8;
      bf16x8 xv;
      if (col < 256) xv = *(const bf16x8*)(Clbf + (size_t)(m0+r)*NCH + col);
      else           xv = *(const bf16x8*)(emb_bf + (size_t)clsL[r]*NCH + (col-256));
      *(bf16x8*)&Xs[r*40 + kb*8] = xv;
      *(bf16x8*)&Ws[r*40 + kb*8] = *(const bf16x8*)(W + (size_t)(n0+r)*K + k0 + kb*8);
    }
    __syncthreads();
    bf16x8 af[4], bg[4];
    #pragma unroll
    for (int m=0;m<4;m++) af[m] = *(const bf16x8*)&Xs[(wr*64 + m*16 + lr)*40 + lk];
    #pragma unroll
    for (int n=0;n<4;n++) bg[n] = *(const bf16x8*)&Ws[(wc*64 + n*16 + lr)*40 + lk];
    #pragma unroll
    for (int m=0;m<4;m++)
      #pragma unroll
      for (int n=0;n<4;n++)
        acc[m][n] = __builtin_amdgcn_mfma_f32_16x16x32_bf16(af[m], bg[n], acc[m][n], 0, 0, 0);
  }
  float bsv[4];
  #pragma unroll
  for (int n=0;n<4;n++) bsv[n] = ba[n0 + wc*64 + n*16 + lr];
  #pragma unroll
  for (int m=0;m<4;m++)
    #pragma unroll
    for (int n=0;n<4;n++)
      #pragma unroll
      for (int j=0;j<4;j++){
        int row = m0 + wr*64 + m*16 + (lane>>4)*4 + j;
        int col = n0 + wc*64 + n*16 + lr;
        out[(size_t)row*N + col] = acc[m][n][j] + bsv[n];
      }
}

// ---------------- K7: packed normalized attention output ----------------
__global__ __launch_bounds__(256) void k_attns(const float* __restrict__ A, const float* __restrict__ S,
    const int* __restrict__ pack_b, const int* __restrict__ pack_t, float* __restrict__ outA){
  int i = blockIdx.x;
  int b = pack_b[i], t = pack_t[i];
  float is = 1.f / S[b*64 + t];
  float4 v = ((const float4*)(A + ((size_t)(b*64+t))*NHW))[threadIdx.x];
  v.x*=is; v.y*=is; v.z*=is; v.w*=is;
  ((float4*)(outA + (size_t)i*NHW))[threadIdx.x] = v;
}

// ---------------- K3: BiLSTM scan, dot2+readlane, W resident in LDS (R17 version) ----------
__global__ __launch_bounds__(512) void k_lstm_ldsT(const float* __restrict__ Gf, const float* __restrict__ Gb,
    const f16_t* __restrict__ Whf, const f16_t* __restrict__ Whb, ushort_t* __restrict__ Clbf){
  extern __shared__ char smem[];
  int2*  Wt2   = (int2*)smem;                       // 131072 B
  float* h32   = (float*)(smem + 131072);           // 128 f32
  float* gates = (float*)(smem + 131072 + 512);     // 512 f32
  int b = blockIdx.x & 127, dir = blockIdx.x >> 7;
  const f16_t* W = dir ? Whb : Whf;                 // [512][128]
  const float* G = dir ? Gb : Gf;                   // [t][128][512] (biases folded)
  int g = threadIdx.x, lane = g & 63;
  {
    const int2* wr = (const int2*)(W + (size_t)g*128);
    #pragma unroll
    for (int p2=0;p2<32;p2++) Wt2[p2*512 + g] = wr[p2];
  }
  if (g < 128) h32[g] = 0.f;
  float c = 0.f;
  __syncthreads();
  #pragma unroll 1
  for (int t=0;t<NTIME;t++){
    int tt = dir ? (NTIME-1-t) : t;
    float gv = G[((size_t)tt*NBATCH + b)*512 + g];
    float2 hp2 = *(const float2*)(h32 + 2*lane);
    int hpk = __builtin_bit_cast(int, pack2(hp2.x, hp2.y));
    float a0=0.f, a1=0.f, a2=0.f, a3=0.f;
    #pragma unroll
    for (int p2=0;p2<32;p2+=2){
      int2 w0 = Wt2[p2*512 + g];
      int2 w1 = Wt2[(p2+1)*512 + g];
      int h0 = __builtin_amdgcn_readlane(hpk, 2*p2);
      int h1 = __builtin_amdgcn_readlane(hpk, 2*p2+1);
      int h2 = __builtin_amdgcn_readlane(hpk, 2*p2+2);
      int h3 = __builtin_amdgcn_readlane(hpk, 2*p2+3);
      a0 = dot2acc(BCH(w0.x), BCH(h0), a0);
      a1 = dot2acc(BCH(w0.y), BCH(h1), a1);
      a2 = dot2acc(BCH(w1.x), BCH(h2), a2);
      a3 = dot2acc(BCH(w1.y), BCH(h3), a3);
    }
    gates[g] = gv + a0+a1+a2+a3;
    __syncthreads();
    if (g < 128){
      float gi=gates[g], gf=gates[128+g], gg=gates[256+g], go=gates[384+g];
      c = sig_(gf)*c + sig_(gi)*tanh_(gg);
      float h = sig_(go)*tanh_(c);
      h32[g] = h;
      Clbf[((size_t)tt*NBATCH + b)*NCH + dir*128 + g] = f2bf(h);
    }
    __syncthreads();
  }
}

// ---------------- K5: GRU scan, 1024 threads (TLP experiment; R7-proven geometry) ----------
// 3072 tasks = 768 rows x 4 k-quarters(64 cols); task c = w*3+s, q=c/12 wave-uniform,
// row=(c%12)*64+lane. 96 weight VGPRs/thread at the 128-reg tier (16 waves -> 4/SIMD).
__global__ __launch_bounds__(1024) void k_gru(const float* __restrict__ gx,
    const float* __restrict__ Whh_g, const float* __restrict__ bhh_g, ushort_t* __restrict__ hsbf){
  int b = blockIdx.x, t0 = threadIdx.x, lane = t0 & 63, w = t0 >> 6;
  half2_t wp[3][32];
  int pidx[3];
  int q16[3];
  #pragma unroll
  for (int s=0;s<3;s++){
    int c = w*3 + s;                  // 0..47
    int q = c/12, rg = c - q*12;      // q 0..3, rg 0..11
    int row = rg*64 + lane;           // 0..767
    pidx[s] = q*768 + row;
    q16[s]  = __builtin_amdgcn_readfirstlane(q*16);
    const float4* wr = (const float4*)(Whh_g + (size_t)row*256 + q*64);
    #pragma unroll
    for (int j=0;j<16;j++){
      float4 v = wr[j];
      wp[s][2*j]   = pack2(v.x, v.y);
      wp[s][2*j+1] = pack2(v.z, v.w);
    }
  }
  __shared__ float h32[256];
  __shared__ float partLds[3072];
  __shared__ float bhL[768];
  if (t0 < 256) h32[t0] = 0.f;
  if (t0 < 768) bhL[t0] = bhh_g[t0];
  float hprev = 0.f;
  __syncthreads();
  #pragma unroll 1
  for (int t=0;t<NTIME;t++){
    float gxr=0.f, gxz=0.f, gxn=0.f;
    if (t0 < 256){
      const float* gxp = gx + ((size_t)t*NBATCH + b)*768;
      gxr = gxp[t0]; gxz = gxp[256+t0]; gxn = gxp[512+t0];
    }
    // lane l holds h[4l..4l+3] as pairs 2l (hpk0) and 2l+1 (hpk1)
    float4 hq = *(const float4*)(h32 + 4*lane);
    int hpk0 = __builtin_bit_cast(int, pack2(hq.x, hq.y));
    int hpk1 = __builtin_bit_cast(int, pack2(hq.z, hq.w));
    #pragma unroll
    for (int s=0;s<3;s++){
      float a0=0.f, a1=0.f, a2=0.f, a3=0.f;
      #pragma unroll
      for (int u=0;u<32;u+=4){
        int h0 = __builtin_amdgcn_readlane(hpk0, q16[s] + (u>>1));
        int h1 = __builtin_amdgcn_readlane(hpk1, q16[s] + (u>>1));
        int h2 = __builtin_amdgcn_readlane(hpk0, q16[s] + (u>>1) + 1);
        int h3 = __builtin_amdgcn_readlane(hpk1, q16[s] + (u>>1) + 1);
        a0 = dot2acc(wp[s][u],   BCH(h0), a0);
        a1 = dot2acc(wp[s][u+1], BCH(h1), a1);
        a2 = dot2acc(wp[s][u+2], BCH(h2), a2);
        a3 = dot2acc(wp[s][u+3], BCH(h3), a3);
      }
      partLds[pidx[s]] = a0+a1+a2+a3;
    }
    __syncthreads();
    if (t0 < 256){
      float rh = bhL[t0]     + partLds[t0]     + partLds[768+t0]      + partLds[1536+t0]      + partLds[2304+t0];
      float zh = bhL[256+t0] + partLds[256+t0] + partLds[768+256+t0]  + partLds[1536+256+t0]  + partLds[2304+256+t0];
      float nh = bhL[512+t0] + partLds[512+t0] + partLds[768+512+t0]  + partLds[1536+512+t0]  + partLds[2304+512+t0];
      float r = sig_(gxr + rh);
      float z = sig_(gxz + zh);
      float n = tanh_(gxn + r*nh);
      float h = (1.f-z)*n + z*hprev;
      hprev = h;
      h32[t0] = h;
      hsbf[((size_t)t*NBATCH + b)*NCH + t0] = f2bf(h);
    }
    __syncthreads();
  }
}

// ---------------- K6: logits via MFMA with row gather ----------------
__global__ __launch_bounds__(256) void k_logits_mfma(const ushort_t* __restrict__ hsbf,
    const int* __restrict__ pack_t, const int* __restrict__ pack_b,
    const ushort_t* __restrict__ Wbf, const float* __restrict__ bias,
    float* __restrict__ out, int L){
  __shared__ ushort_t Xs[64*40];
  __shared__ ushort_t Ws[128*40];
  __shared__ int rrow[64];
  int m0 = blockIdx.x*64;
  int tid = threadIdx.x, wave = tid>>6, lane = tid&63;
  int lr = lane & 15, lk = (lane>>4)*8;
  if (tid < 64){
    int m = m0 + tid;
    int pt = (m<L) ? pack_t[m] : 0;
    int pb = (m<L) ? pack_b[m] : 0;
    rrow[tid] = pt*NBATCH + pb;
  }
  f32x4 acc[4][2] = {};
  for (int k0=0;k0<NCH;k0+=32){
    __syncthreads();
    {
      int r = tid>>2, kb = tid&3;
      *(bf16x8*)&Xs[r*40 + kb*8] = *(const bf16x8*)(hsbf + (size_t)rrow[r]*NCH + k0 + kb*8);
    }
    #pragma unroll
    for (int i=0;i<2;i++){
      int c = tid + i*256, r = c>>2, kb = c&3;
      *(bf16x8*)&Ws[r*40 + kb*8] = *(const bf16x8*)(Wbf + (size_t)r*NCH + k0 + kb*8);
    }
    __syncthreads();
    bf16x8 af[4], bg[2];
    #pragma unroll
    for (int m=0;m<4;m++) af[m] = *(const bf16x8*)&Xs[(m*16 + lr)*40 + lk];
    #pragma unroll
    for (int n=0;n<2;n++) bg[n] = *(const bf16x8*)&Ws[(wave*32 + n*16 + lr)*40 + lk];
    #pragma unroll
    for (int m=0;m<4;m++)
      #pragma unroll
      for (int n=0;n<2;n++)
        acc[m][n] = __builtin_amdgcn_mfma_f32_16x16x32_bf16(af[m], bg[n], acc[m][n], 0, 0, 0);
  }
  #pragma unroll
  for (int m=0;m<4;m++)
    #pragma unroll
    for (int n=0;n<2;n++)
      #pragma unroll
      for (int j=0;j<4;j++){
        int row = m0 + m*16 + (lane>>4)*4 + j;
        int col = wave*32 + n*16 + lr;
        if (row < L) out[(size_t)row*NCLS + col] = acc[m][n][j] + bias[col];
      }
}

extern "C" void kernel_launch(void* const* d_in, const int* in_sizes, int n_in,
                              void* d_out, int out_size, void* d_ws, size_t ws_size,
                              hipStream_t stream) {
  const float* feature = (const float*)d_in[0];
  const float* A       = (const float*)d_in[1];
  const int*   text    = (const int*)d_in[2];
  const int*   pack_b  = (const int*)d_in[4];
  const int*   pack_t  = (const int*)d_in[5];
  const float* emb     = (const float*)d_in[6];
  const float* Wih_f   = (const float*)d_in[7];
  const float* Whh_f   = (const float*)d_in[8];
  const float* bih_f   = (const float*)d_in[9];
  const float* bhh_f   = (const float*)d_in[10];
  const float* Wih_b   = (const float*)d_in[11];
  const float* Whh_b   = (const float*)d_in[12];
  const float* bih_b   = (const float*)d_in[13];
  const float* bhh_b   = (const float*)d_in[14];
  const float* Wih_g   = (const float*)d_in[15];
  const float* Whh_g   = (const float*)d_in[16];
  const float* bih_g   = (const float*)d_in[17];
  const float* bhh_g   = (const float*)d_in[18];
  const float* Wgen    = (const float*)d_in[19];
  const float* bgen    = (const float*)d_in[20];
  int L = in_sizes[4];

  char* ws = (char*)d_ws;
  const size_t KB = 1024, MB = 1u<<20;
  float*    S       = (float*)(ws + 0);                    // 32 KB
  ushort_t* Wf_bf   = (ushort_t*)(ws + 1*MB);              // 256 KB
  ushort_t* Wb_bf   = (ushort_t*)(ws + 1*MB + 256*KB);     // 256 KB
  ushort_t* Wg_bf   = (ushort_t*)(ws + 1*MB + 512*KB);     // 768 KB
  ushort_t* Wgen_bf = (ushort_t*)(ws + 2*MB + 256*KB);     // 64 KB
  f16_t*    Whf_h   = (f16_t*)(ws + 2*MB + 512*KB);        // 128 KB
  f16_t*    Whb_h   = (f16_t*)(ws + 2*MB + 640*KB);        // 128 KB
  f16_t*    Whg_h   = (f16_t*)(ws + 2*MB + 768*KB);        // 384 KB
  ushort_t* emb_bf  = (ushort_t*)(ws + 3*MB + 256*KB);     // 64 KB
  ushort_t* Cbf     = (ushort_t*)(ws + 4*MB);              // 4 MB
  ushort_t* Clbf    = (ushort_t*)(ws + 8*MB);              // 4 MB
  ushort_t* hsbf    = (ushort_t*)(ws + 12*MB);             // 4 MB
  float*    Gf      = (float*)(ws + 16*MB);                // 16 MB (dead after k_lstm)
  float*    Gb      = (float*)(ws + 32*MB);                // 16 MB (dead after k_lstm)
  float*    gx      = (float*)(ws + 24*MB);                // 25.2 MB, aliases Gb+ (after lstm)

  float* out_res   = (float*)d_out;
  float* out_attns = out_res + (size_t)L*NCLS;

  const int LSTM_SMEM = 131072 + 512 + 2048;               // 133,632 B
  (void)hipFuncSetAttribute((const void*)k_lstm_ldsT,
                            hipFuncAttributeMaxDynamicSharedMemorySize, LSTM_SMEM);

  k_prep<<<4096, 256, 0, stream>>>(Wih_f, Wih_b, Wih_g, Wgen, Whh_f, Whh_b, Whh_g, emb,
                                   Wf_bf, Wb_bf, Wg_bf, Wgen_bf, Whf_h, Whb_h, Whg_h, emb_bf);
  k_pool_mfma<<<256, 256, 0, stream>>>(feature, A, S, Cbf);
  k_attns<<<L, 256, 0, stream>>>(A, S, pack_b, pack_t, out_attns);
  k_gemm_bf<<<dim3(4,64), 256, 0, stream>>>(Cbf, Wf_bf, bih_f, bhh_f, Gf, 512, 256);
  k_gemm_bf<<<dim3(4,64), 256, 0, stream>>>(Cbf, Wb_bf, bih_b, bhh_b, Gb, 512, 256);
  k_lstm_ldsT<<<256, 512, LSTM_SMEM, stream>>>(Gf, Gb, Whf_h, Whb_h, Clbf);
  k_gemm_gx<<<dim3(6,64), 256, 0, stream>>>(Clbf, emb_bf, text, Wg_bf, bih_g, gx);
  k_gru<<<128, 1024, 0, stream>>>(gx, Whh_g, bhh_g, hsbf);
  k_logits_mfma<<<(L+63)/64, 256, 0, stream>>>(hsbf, pack_t, pack_b, Wgen_bf, bgen, out_res, L);
}

// Round 20
// 316.031 us; speedup vs baseline: 1.2577x; 1.2577x over previous
//
#include <hip/hip_runtime.h>
#include <cstdint>
#include <cstddef>

#define NBATCH 128
#define NCH    256
#define NHW    1024
#define NTIME  64
#define NCLS   128
#define NATTN  256   // extra blocks in k_gru doing packed-attn output

typedef _Float16 f16_t;
typedef _Float16 f16x8 __attribute__((ext_vector_type(8)));
typedef _Float16 half2_t __attribute__((ext_vector_type(2)));
typedef short bf16x8 __attribute__((ext_vector_type(8)));
typedef short bf16x4 __attribute__((ext_vector_type(4)));
typedef float f32x4 __attribute__((ext_vector_type(4)));
typedef unsigned short ushort_t;

#if defined(__has_builtin)
#  if __has_builtin(__builtin_amdgcn_fdot2)
#    define HAS_FDOT2 1
#  endif
#endif
#ifndef HAS_FDOT2
#  define HAS_FDOT2 0
#endif

__device__ __forceinline__ float dot2acc(half2_t a, half2_t b, float c){
#if HAS_FDOT2
  return __builtin_amdgcn_fdot2(a, b, c, false);
#else
  return c + (float)a.x*(float)b.x + (float)a.y*(float)b.y;
#endif
}
__device__ __forceinline__ half2_t pack2(float x, float y){
  half2_t p; p.x = (_Float16)x; p.y = (_Float16)y; return p;
}
#define BCH(x) __builtin_bit_cast(half2_t, (x))
__device__ __forceinline__ ushort_t f2bf(float x){
  unsigned u = __builtin_bit_cast(unsigned, x);
  unsigned r = (u + 0x7FFFu + ((u>>16)&1u)) >> 16;
  return (ushort_t)r;
}
__device__ __forceinline__ float sig_(float x){
  x = fminf(30.f, fmaxf(-30.f, x));
  return 1.f/(1.f+__expf(-x));
}
__device__ __forceinline__ float tanh_(float x){
  x = fminf(15.f, fmaxf(-15.f, x));
  float e = __expf(2.f*x);
  return (e-1.f)/(e+1.f);
}

// ---------------- K-prep: ALL weight conversions in one kernel ----------------
__global__ __launch_bounds__(256) void k_prep(
    const float* __restrict__ Wih_f, const float* __restrict__ Wih_b,
    const float* __restrict__ Wih_g, const float* __restrict__ Wgen,
    const float* __restrict__ Whh_f, const float* __restrict__ Whh_b,
    const float* __restrict__ Whh_g, const float* __restrict__ emb,
    ushort_t* __restrict__ Wf_bf, ushort_t* __restrict__ Wb_bf,
    ushort_t* __restrict__ Wg_bf, ushort_t* __restrict__ Wgen_bf,
    f16_t* __restrict__ Whf_h, f16_t* __restrict__ Whb_h, f16_t* __restrict__ Whg_h,
    ushort_t* __restrict__ emb_bf){
  int i = blockIdx.x*256 + threadIdx.x;
  if (i < 131072){ Wf_bf[i] = f2bf(Wih_f[i]); return; }
  i -= 131072;
  if (i < 131072){ Wb_bf[i] = f2bf(Wih_b[i]); return; }
  i -= 131072;
  if (i < 393216){ Wg_bf[i] = f2bf(Wih_g[i]); return; }
  i -= 393216;
  if (i < 32768){ Wgen_bf[i] = f2bf(Wgen[i]); return; }
  i -= 32768;
  if (i < 65536){ Whf_h[i] = (f16_t)Whh_f[i]; return; }
  i -= 65536;
  if (i < 65536){ Whb_h[i] = (f16_t)Whh_b[i]; return; }
  i -= 65536;
  if (i < 196608){ Whg_h[i] = (f16_t)Whh_g[i]; return; }
  i -= 196608;
  emb_bf[i] = f2bf(emb[i]);
}

// ---------------- K1: attention pooling via MFMA + fused row-sum ----------------
__global__ __launch_bounds__(256) void k_pool_mfma(const float* __restrict__ feat, const float* __restrict__ A,
    float* __restrict__ S, ushort_t* __restrict__ Cbf){
  __shared__ ushort_t As_[64*40];
  __shared__ ushort_t Fs_[128*40];
  __shared__ float sinvs[64];
  __shared__ float psum[512];
  int b = blockIdx.x >> 1, ch = blockIdx.x & 1, c0 = ch*128;
  int tid = threadIdx.x, wave = tid>>6, lane = tid&63;
  f32x4 acc[4][2] = {};
  int lr = lane & 15, lk = (lane>>4)*8;
  float sA0 = 0.f, sA1 = 0.f;
  for (int k0=0;k0<NHW;k0+=32){
    __syncthreads();
    #pragma unroll
    for (int i=0;i<2;i++){
      int c = tid + i*256, r = c>>3, kq = c&7;
      float4 v = *(const float4*)(A + ((size_t)(b*64+r))*NHW + k0 + kq*4);
      float sv = v.x+v.y+v.z+v.w;
      if (i==0) sA0 += sv; else sA1 += sv;
      bf16x4 p; p[0]=(short)f2bf(v.x); p[1]=(short)f2bf(v.y); p[2]=(short)f2bf(v.z); p[3]=(short)f2bf(v.w);
      *(bf16x4*)&As_[r*40 + kq*4] = p;
    }
    #pragma unroll
    for (int i=0;i<4;i++){
      int c = tid + i*256, r = c>>3, kq = c&7;
      float4 v = *(const float4*)(feat + ((size_t)(b*256+c0+r))*NHW + k0 + kq*4);
      bf16x4 p; p[0]=(short)f2bf(v.x); p[1]=(short)f2bf(v.y); p[2]=(short)f2bf(v.z); p[3]=(short)f2bf(v.w);
      *(bf16x4*)&Fs_[r*40 + kq*4] = p;
    }
    __syncthreads();
    bf16x8 af[4], bg[2];
    #pragma unroll
    for (int m=0;m<4;m++) af[m] = *(const bf16x8*)&As_[(m*16 + lr)*40 + lk];
    #pragma unroll
    for (int n=0;n<2;n++) bg[n] = *(const bf16x8*)&Fs_[(wave*32 + n*16 + lr)*40 + lk];
    #pragma unroll
    for (int m=0;m<4;m++)
      #pragma unroll
      for (int n=0;n<2;n++)
        acc[m][n] = __builtin_amdgcn_mfma_f32_16x16x32_bf16(af[m], bg[n], acc[m][n], 0, 0, 0);
  }
  psum[tid] = sA0;
  psum[tid+256] = sA1;
  __syncthreads();
  if (tid < 64){
    float s = 0.f;
    #pragma unroll
    for (int j=0;j<8;j++) s += psum[tid*8 + j];
    sinvs[tid] = 1.f / s;
    if (ch == 0) S[b*64 + tid] = s;
  }
  __syncthreads();
  #pragma unroll
  for (int m=0;m<4;m++)
    #pragma unroll
    for (int n=0;n<2;n++)
      #pragma unroll
      for (int j=0;j<4;j++){
        int t = m*16 + (lane>>4)*4 + j;
        int c = c0 + wave*32 + n*16 + lr;
        Cbf[((size_t)t*NBATCH + b)*NCH + c] = f2bf(acc[m][n][j] * sinvs[t]);
      }
}

// ---------------- generic bf16 MFMA GEMM ----------------
__global__ __launch_bounds__(256) void k_gemm_bf(const ushort_t* __restrict__ X, const ushort_t* __restrict__ W,
    const float* __restrict__ ba, const float* __restrict__ bb, float* __restrict__ out, int N, int K){
  __shared__ ushort_t Xs[128*40];
  __shared__ ushort_t Ws[128*40];
  int n0 = blockIdx.x*128, m0 = blockIdx.y*128;
  int tid = threadIdx.x, wave = tid>>6, lane = tid&63;
  int wr = wave>>1, wc = wave&1;
  int lr = lane & 15, lk = (lane>>4)*8;
  f32x4 acc[4][4] = {};
  for (int k0=0;k0<K;k0+=32){
    __syncthreads();
    #pragma unroll
    for (int i=0;i<2;i++){
      int c = tid + i*256, r = c>>2, kb = c&3;
      *(bf16x8*)&Xs[r*40 + kb*8] = *(const bf16x8*)(X + (size_t)(m0+r)*K + k0 + kb*8);
      *(bf16x8*)&Ws[r*40 + kb*8] = *(const bf16x8*)(W + (size_t)(n0+r)*K + k0 + kb*8);
    }
    __syncthreads();
    bf16x8 af[4], bg[4];
    #pragma unroll
    for (int m=0;m<4;m++) af[m] = *(const bf16x8*)&Xs[(wr*64 + m*16 + lr)*40 + lk];
    #pragma unroll
    for (int n=0;n<4;n++) bg[n] = *(const bf16x8*)&Ws[(wc*64 + n*16 + lr)*40 + lk];
    #pragma unroll
    for (int m=0;m<4;m++)
      #pragma unroll
      for (int n=0;n<4;n++)
        acc[m][n] = __builtin_amdgcn_mfma_f32_16x16x32_bf16(af[m], bg[n], acc[m][n], 0, 0, 0);
  }
  float bsv[4];
  #pragma unroll
  for (int n=0;n<4;n++){
    int col = n0 + wc*64 + n*16 + lr;
    bsv[n] = ba[col] + (bb ? bb[col] : 0.f);
  }
  #pragma unroll
  for (int m=0;m<4;m++)
    #pragma unroll
    for (int n=0;n<4;n++)
      #pragma unroll
      for (int j=0;j<4;j++){
        int row = m0 + wr*64 + m*16 + (lane>>4)*4 + j;
        int col = n0 + wc*64 + n*16 + lr;
        out[(size_t)row*N + col] = acc[m][n][j] + bsv[n];
      }
}

// ---------------- gx GEMM with fused xs-gather ----------------
__global__ __launch_bounds__(256) void k_gemm_gx(const ushort_t* __restrict__ Clbf,
    const ushort_t* __restrict__ emb_bf, const int* __restrict__ text,
    const ushort_t* __restrict__ W, const float* __restrict__ ba,
    float* __restrict__ out){
  __shared__ ushort_t Xs[128*40];
  __shared__ ushort_t Ws[128*40];
  __shared__ int clsL[128];
  const int N = 768, K = 512;
  int n0 = blockIdx.x*128, m0 = blockIdx.y*128;
  int tid = threadIdx.x, wave = tid>>6, lane = tid&63;
  int wr = wave>>1, wc = wave&1;
  int lr = lane & 15, lk = (lane>>4)*8;
  if (tid < 128){
    int m = m0 + tid, t = m>>7, b = m&127;
    clsL[tid] = (t==0) ? 0 : text[b*64 + (t-1)];
  }
  f32x4 acc[4][4] = {};
  __syncthreads();
  for (int k0=0;k0<K;k0+=32){
    __syncthreads();
    #pragma unroll
    for (int i=0;i<2;i++){
      int c = tid + i*256, r = c>>2, kb = c&3;
      int col = k0 + kb*8;
      bf16x8 xv;
      if (col < 256) xv = *(const bf16x8*)(Clbf + (size_t)(m0+r)*NCH + col);
      else           xv = *(const bf16x8*)(emb_bf + (size_t)clsL[r]*NCH + (col-256));
      *(bf16x8*)&Xs[r*40 + kb*8] = xv;
      *(bf16x8*)&Ws[r*40 + kb*8] = *(const bf16x8*)(W + (size_t)(n0+r)*K + k0 + kb*8);
    }
    __syncthreads();
    bf16x8 af[4], bg[4];
    #pragma unroll
    for (int m=0;m<4;m++) af[m] = *(const bf16x8*)&Xs[(wr*64 + m*16 + lr)*40 + lk];
    #pragma unroll
    for (int n=0;n<4;n++) bg[n] = *(const bf16x8*)&Ws[(wc*64 + n*16 + lr)*40 + lk];
    #pragma unroll
    for (int m=0;m<4;m++)
      #pragma unroll
      for (int n=0;n<4;n++)
        acc[m][n] = __builtin_amdgcn_mfma_f32_16x16x32_bf16(af[m], bg[n], acc[m][n], 0, 0, 0);
  }
  float bsv[4];
  #pragma unroll
  for (int n=0;n<4;n++) bsv[n] = ba[n0 + wc*64 + n*16 + lr];
  #pragma unroll
  for (int m=0;m<4;m++)
    #pragma unroll
    for (int n=0;n<4;n++)
      #pragma unroll
      for (int j=0;j<4;j++){
        int row = m0 + wr*64 + m*16 + (lane>>4)*4 + j;
        int col = n0 + wc*64 + n*16 + lr;
        out[(size_t)row*N + col] = acc[m][n][j] + bsv[n];
      }
}

// ---------------- K3: BiLSTM scan, dot2+readlane, W resident in LDS (R17 version) ----------
__global__ __launch_bounds__(512) void k_lstm_ldsT(const float* __restrict__ Gf, const float* __restrict__ Gb,
    const f16_t* __restrict__ Whf, const f16_t* __restrict__ Whb, ushort_t* __restrict__ Clbf){
  extern __shared__ char smem[];
  int2*  Wt2   = (int2*)smem;                       // 131072 B
  float* h32   = (float*)(smem + 131072);           // 128 f32
  float* gates = (float*)(smem + 131072 + 512);     // 512 f32
  int b = blockIdx.x & 127, dir = blockIdx.x >> 7;
  const f16_t* W = dir ? Whb : Whf;                 // [512][128]
  const float* G = dir ? Gb : Gf;                   // [t][128][512] (biases folded)
  int g = threadIdx.x, lane = g & 63;
  {
    const int2* wr = (const int2*)(W + (size_t)g*128);
    #pragma unroll
    for (int p2=0;p2<32;p2++) Wt2[p2*512 + g] = wr[p2];
  }
  if (g < 128) h32[g] = 0.f;
  float c = 0.f;
  __syncthreads();
  #pragma unroll 1
  for (int t=0;t<NTIME;t++){
    int tt = dir ? (NTIME-1-t) : t;
    float gv = G[((size_t)tt*NBATCH + b)*512 + g];
    float2 hp2 = *(const float2*)(h32 + 2*lane);
    int hpk = __builtin_bit_cast(int, pack2(hp2.x, hp2.y));
    float a0=0.f, a1=0.f, a2=0.f, a3=0.f;
    #pragma unroll
    for (int p2=0;p2<32;p2+=2){
      int2 w0 = Wt2[p2*512 + g];
      int2 w1 = Wt2[(p2+1)*512 + g];
      int h0 = __builtin_amdgcn_readlane(hpk, 2*p2);
      int h1 = __builtin_amdgcn_readlane(hpk, 2*p2+1);
      int h2 = __builtin_amdgcn_readlane(hpk, 2*p2+2);
      int h3 = __builtin_amdgcn_readlane(hpk, 2*p2+3);
      a0 = dot2acc(BCH(w0.x), BCH(h0), a0);
      a1 = dot2acc(BCH(w0.y), BCH(h1), a1);
      a2 = dot2acc(BCH(w1.x), BCH(h2), a2);
      a3 = dot2acc(BCH(w1.y), BCH(h3), a3);
    }
    gates[g] = gv + a0+a1+a2+a3;
    __syncthreads();
    if (g < 128){
      float gi=gates[g], gf=gates[128+g], gg=gates[256+g], go=gates[384+g];
      c = sig_(gf)*c + sig_(gi)*tanh_(gg);
      float h = sig_(go)*tanh_(c);
      h32[g] = h;
      Clbf[((size_t)tt*NBATCH + b)*NCH + dir*128 + g] = f2bf(h);
    }
    __syncthreads();
  }
}

// ---------------- K5: GRU scan (R17-proven) + fused packed-attn blocks ----------------
// Blocks 0..127: GRU (512 thr, 3 reg-chunk tasks). Blocks 128..128+NATTN-1: grid-stride
// over packed rows, 2 rows per iteration (thread halves), hiding k_attns under the scan.
__global__ __launch_bounds__(512, 1) void k_gru(const float* __restrict__ gx,
    const float* __restrict__ Whh_g, const float* __restrict__ bhh_g, ushort_t* __restrict__ hsbf,
    const float* __restrict__ A, const float* __restrict__ S,
    const int* __restrict__ pack_b, const int* __restrict__ pack_t,
    float* __restrict__ outA, int L){
  int b = blockIdx.x, t0 = threadIdx.x, lane = t0 & 63, w = t0 >> 6;
  if (b >= NBATCH){
    // ---- packed-attention copy path ----
    int ab = b - NBATCH;
    int half = t0 >> 8, q = t0 & 255;     // 2 rows/iter; thread-half picks row
    for (int r0 = ab*2; r0 < L; r0 += NATTN*2){
      int r = r0 + half;
      if (r < L){
        int bb = pack_b[r], tt = pack_t[r];
        float is = 1.f / S[bb*64 + tt];
        float4 v = ((const float4*)(A + ((size_t)(bb*64+tt))*NHW))[q];
        v.x*=is; v.y*=is; v.z*=is; v.w*=is;
        ((float4*)(outA + (size_t)r*NHW))[q] = v;
      }
    }
    return;
  }
  half2_t wpA[64], wpB[64], wpC[64];
  int pidxA, pidxB, pidxC;
  int hfbA, hfbB, hfbC;

#define LOADW(WP, PIDX, HFB, S_) do { \
    int c = w*3 + (S_); \
    int hf = (c >= 12) ? 1 : 0; \
    int row = (c - hf*12)*64 + lane; \
    PIDX = hf*768 + row; \
    HFB  = __builtin_amdgcn_readfirstlane(hf*32); \
    const float4* wr = (const float4*)(Whh_g + (size_t)row*256 + hf*128); \
    _Pragma("unroll") \
    for (int j=0;j<32;j++){ \
      float4 v = wr[j]; \
      WP[2*j]   = pack2(v.x, v.y); \
      WP[2*j+1] = pack2(v.z, v.w); \
    } \
  } while(0)

  LOADW(wpA, pidxA, hfbA, 0);
  LOADW(wpB, pidxB, hfbB, 1);
  LOADW(wpC, pidxC, hfbC, 2);
#undef LOADW

  __shared__ float h32[256];
  __shared__ float partLds[1536];
  __shared__ float bhL[768];
  if (t0 < 256) h32[t0] = 0.f;
  bhL[t0] = bhh_g[t0];
  if (t0 < 256) bhL[512+t0] = bhh_g[512+t0];
  float hprev = 0.f;
  __syncthreads();
  #pragma unroll 1
  for (int t=0;t<NTIME;t++){
    float gxr=0.f, gxz=0.f, gxn=0.f;
    if (t0 < 256){
      const float* gxp = gx + ((size_t)t*NBATCH + b)*768;
      gxr = gxp[t0]; gxz = gxp[256+t0]; gxn = gxp[512+t0];
    }
    float4 hq = *(const float4*)(h32 + 4*lane);
    int hpk0 = __builtin_bit_cast(int, pack2(hq.x, hq.y));
    int hpk1 = __builtin_bit_cast(int, pack2(hq.z, hq.w));

#define DOTASK(WP, PIDX, HFB) do { \
    float a0=0.f, a1=0.f, a2=0.f, a3=0.f; \
    _Pragma("unroll") \
    for (int jj=0;jj<64;jj+=2){ \
      int hv0 = __builtin_amdgcn_readlane(hpk0, HFB + (jj>>1)); \
      int hv1 = __builtin_amdgcn_readlane(hpk1, HFB + (jj>>1)); \
      if ((jj>>1)&1){ \
        a2 = dot2acc(WP[jj],   __builtin_bit_cast(half2_t, hv0), a2); \
        a3 = dot2acc(WP[jj+1], __builtin_bit_cast(half2_t, hv1), a3); \
      } else { \
        a0 = dot2acc(WP[jj],   __builtin_bit_cast(half2_t, hv0), a0); \
        a1 = dot2acc(WP[jj+1], __builtin_bit_cast(half2_t, hv1), a1); \
      } \
    } \
    partLds[PIDX] = a0+a1+a2+a3; \
  } while(0)

    DOTASK(wpA, pidxA, hfbA);
    DOTASK(wpB, pidxB, hfbB);
    DOTASK(wpC, pidxC, hfbC);
#undef DOTASK

    __syncthreads();
    if (t0 < 256){
      float rh = bhL[t0]     + partLds[t0]     + partLds[768+t0];
      float zh = bhL[256+t0] + partLds[256+t0] + partLds[1024+t0];
      float nh = bhL[512+t0] + partLds[512+t0] + partLds[1280+t0];
      float r = sig_(gxr + rh);
      float z = sig_(gxz + zh);
      float n = tanh_(gxn + r*nh);
      float h = (1.f-z)*n + z*hprev;
      hprev = h;
      h32[t0] = h;
      hsbf[((size_t)t*NBATCH + b)*NCH + t0] = f2bf(h);
    }
    __syncthreads();
  }
}

// ---------------- K6: logits via MFMA with row gather ----------------
__global__ __launch_bounds__(256) void k_logits_mfma(const ushort_t* __restrict__ hsbf,
    const int* __restrict__ pack_t, const int* __restrict__ pack_b,
    const ushort_t* __restrict__ Wbf, const float* __restrict__ bias,
    float* __restrict__ out, int L){
  __shared__ ushort_t Xs[64*40];
  __shared__ ushort_t Ws[128*40];
  __shared__ int rrow[64];
  int m0 = blockIdx.x*64;
  int tid = threadIdx.x, wave = tid>>6, lane = tid&63;
  int lr = lane & 15, lk = (lane>>4)*8;
  if (tid < 64){
    int m = m0 + tid;
    int pt = (m<L) ? pack_t[m] : 0;
    int pb = (m<L) ? pack_b[m] : 0;
    rrow[tid] = pt*NBATCH + pb;
  }
  f32x4 acc[4][2] = {};
  for (int k0=0;k0<NCH;k0+=32){
    __syncthreads();
    {
      int r = tid>>2, kb = tid&3;
      *(bf16x8*)&Xs[r*40 + kb*8] = *(const bf16x8*)(hsbf + (size_t)rrow[r]*NCH + k0 + kb*8);
    }
    #pragma unroll
    for (int i=0;i<2;i++){
      int c = tid + i*256, r = c>>2, kb = c&3;
      *(bf16x8*)&Ws[r*40 + kb*8] = *(const bf16x8*)(Wbf + (size_t)r*NCH + k0 + kb*8);
    }
    __syncthreads();
    bf16x8 af[4], bg[2];
    #pragma unroll
    for (int m=0;m<4;m++) af[m] = *(const bf16x8*)&Xs[(m*16 + lr)*40 + lk];
    #pragma unroll
    for (int n=0;n<2;n++) bg[n] = *(const bf16x8*)&Ws[(wave*32 + n*16 + lr)*40 + lk];
    #pragma unroll
    for (int m=0;m<4;m++)
      #pragma unroll
      for (int n=0;n<2;n++)
        acc[m][n] = __builtin_amdgcn_mfma_f32_16x16x32_bf16(af[m], bg[n], acc[m][n], 0, 0, 0);
  }
  #pragma unroll
  for (int m=0;m<4;m++)
    #pragma unroll
    for (int n=0;n<2;n++)
      #pragma unroll
      for (int j=0;j<4;j++){
        int row = m0 + m*16 + (lane>>4)*4 + j;
        int col = wave*32 + n*16 + lr;
        if (row < L) out[(size_t)row*NCLS + col] = acc[m][n][j] + bias[col];
      }
}

extern "C" void kernel_launch(void* const* d_in, const int* in_sizes, int n_in,
                              void* d_out, int out_size, void* d_ws, size_t ws_size,
                              hipStream_t stream) {
  const float* feature = (const float*)d_in[0];
  const float* A       = (const float*)d_in[1];
  const int*   text    = (const int*)d_in[2];
  const int*   pack_b  = (const int*)d_in[4];
  const int*   pack_t  = (const int*)d_in[5];
  const float* emb     = (const float*)d_in[6];
  const float* Wih_f   = (const float*)d_in[7];
  const float* Whh_f   = (const float*)d_in[8];
  const float* bih_f   = (const float*)d_in[9];
  const float* bhh_f   = (const float*)d_in[10];
  const float* Wih_b   = (const float*)d_in[11];
  const float* Whh_b   = (const float*)d_in[12];
  const float* bih_b   = (const float*)d_in[13];
  const float* bhh_b   = (const float*)d_in[14];
  const float* Wih_g   = (const float*)d_in[15];
  const float* Whh_g   = (const float*)d_in[16];
  const float* bih_g   = (const float*)d_in[17];
  const float* bhh_g   = (const float*)d_in[18];
  const float* Wgen    = (const float*)d_in[19];
  const float* bgen    = (const float*)d_in[20];
  int L = in_sizes[4];

  char* ws = (char*)d_ws;
  const size_t KB = 1024, MB = 1u<<20;
  float*    S       = (float*)(ws + 0);                    // 32 KB
  ushort_t* Wf_bf   = (ushort_t*)(ws + 1*MB);              // 256 KB
  ushort_t* Wb_bf   = (ushort_t*)(ws + 1*MB + 256*KB);     // 256 KB
  ushort_t* Wg_bf   = (ushort_t*)(ws + 1*MB + 512*KB);     // 768 KB
  ushort_t* Wgen_bf = (ushort_t*)(ws + 2*MB + 256*KB);     // 64 KB
  f16_t*    Whf_h   = (f16_t*)(ws + 2*MB + 512*KB);        // 128 KB
  f16_t*    Whb_h   = (f16_t*)(ws + 2*MB + 640*KB);        // 128 KB
  f16_t*    Whg_h   = (f16_t*)(ws + 2*MB + 768*KB);        // 384 KB
  ushort_t* emb_bf  = (ushort_t*)(ws + 3*MB + 256*KB);     // 64 KB
  ushort_t* Cbf     = (ushort_t*)(ws + 4*MB);              // 4 MB
  ushort_t* Clbf    = (ushort_t*)(ws + 8*MB);              // 4 MB
  ushort_t* hsbf    = (ushort_t*)(ws + 12*MB);             // 4 MB
  float*    Gf      = (float*)(ws + 16*MB);                // 16 MB (dead after k_lstm)
  float*    Gb      = (float*)(ws + 32*MB);                // 16 MB (dead after k_lstm)
  float*    gx      = (float*)(ws + 24*MB);                // 25.2 MB, aliases Gb+ (after lstm)

  float* out_res   = (float*)d_out;
  float* out_attns = out_res + (size_t)L*NCLS;

  const int LSTM_SMEM = 131072 + 512 + 2048;               // 133,632 B
  (void)hipFuncSetAttribute((const void*)k_lstm_ldsT,
                            hipFuncAttributeMaxDynamicSharedMemorySize, LSTM_SMEM);

  k_prep<<<4096, 256, 0, stream>>>(Wih_f, Wih_b, Wih_g, Wgen, Whh_f, Whh_b, Whh_g, emb,
                                   Wf_bf, Wb_bf, Wg_bf, Wgen_bf, Whf_h, Whb_h, Whg_h, emb_bf);
  k_pool_mfma<<<256, 256, 0, stream>>>(feature, A, S, Cbf);
  k_gemm_bf<<<dim3(4,64), 256, 0, stream>>>(Cbf, Wf_bf, bih_f, bhh_f, Gf, 512, 256);
  k_gemm_bf<<<dim3(4,64), 256, 0, stream>>>(Cbf, Wb_bf, bih_b, bhh_b, Gb, 512, 256);
  k_lstm_ldsT<<<256, 512, LSTM_SMEM, stream>>>(Gf, Gb, Whf_h, Whb_h, Clbf);
  k_gemm_gx<<<dim3(6,64), 256, 0, stream>>>(Clbf, emb_bf, text, Wg_bf, bih_g, gx);
  k_gru<<<NBATCH + NATTN, 512, 0, stream>>>(gx, Whh_g, bhh_g, hsbf,
                                            A, S, pack_b, pack_t, out_attns, L);
  k_logits_mfma<<<(L+63)/64, 256, 0, stream>>>(hsbf, pack_t, pack_b, Wgen_bf, bgen, out_res, L);
}

// Round 21
// 309.811 us; speedup vs baseline: 1.2830x; 1.0201x over previous
//
#include <hip/hip_runtime.h>
#include <cstdint>
#include <cstddef>

#define NBATCH 128
#define NCH    256
#define NHW    1024
#define NTIME  64
#define NCLS   128
#define NATTN  256   // extra blocks in k_gru doing packed-attn output
#define NPREP  64    // extra blocks in k_pool doing weight conversion

typedef _Float16 f16_t;
typedef _Float16 f16x8 __attribute__((ext_vector_type(8)));
typedef _Float16 half2_t __attribute__((ext_vector_type(2)));
typedef short bf16x8 __attribute__((ext_vector_type(8)));
typedef short bf16x4 __attribute__((ext_vector_type(4)));
typedef float f32x4 __attribute__((ext_vector_type(4)));
typedef unsigned short ushort_t;

#if defined(__has_builtin)
#  if __has_builtin(__builtin_amdgcn_fdot2)
#    define HAS_FDOT2 1
#  endif
#endif
#ifndef HAS_FDOT2
#  define HAS_FDOT2 0
#endif

__device__ __forceinline__ float dot2acc(half2_t a, half2_t b, float c){
#if HAS_FDOT2
  return __builtin_amdgcn_fdot2(a, b, c, false);
#else
  return c + (float)a.x*(float)b.x + (float)a.y*(float)b.y;
#endif
}
__device__ __forceinline__ half2_t pack2(float x, float y){
  half2_t p; p.x = (_Float16)x; p.y = (_Float16)y; return p;
}
#define BCH(x) __builtin_bit_cast(half2_t, (x))
__device__ __forceinline__ ushort_t f2bf(float x){
  unsigned u = __builtin_bit_cast(unsigned, x);
  unsigned r = (u + 0x7FFFu + ((u>>16)&1u)) >> 16;
  return (ushort_t)r;
}
__device__ __forceinline__ float sig_(float x){
  x = fminf(30.f, fmaxf(-30.f, x));
  return 1.f/(1.f+__expf(-x));
}
__device__ __forceinline__ float tanh_(float x){
  x = fminf(15.f, fmaxf(-15.f, x));
  float e = __expf(2.f*x);
  return (e-1.f)/(e+1.f);
}

// ---- weight-conversion worker (segments as in R17 k_prep), element i of 1,048,576 ----
__device__ __forceinline__ void prep_elem(int i,
    const float* __restrict__ Wih_f, const float* __restrict__ Wih_b,
    const float* __restrict__ Wih_g, const float* __restrict__ Wgen,
    const float* __restrict__ Whh_f, const float* __restrict__ Whh_b,
    const float* __restrict__ Whh_g, const float* __restrict__ emb,
    ushort_t* __restrict__ Wf_bf, ushort_t* __restrict__ Wb_bf,
    ushort_t* __restrict__ Wg_bf, ushort_t* __restrict__ Wgen_bf,
    f16_t* __restrict__ Whf_h, f16_t* __restrict__ Whb_h, f16_t* __restrict__ Whg_h,
    ushort_t* __restrict__ emb_bf){
  if (i < 131072){ Wf_bf[i] = f2bf(Wih_f[i]); return; }
  i -= 131072;
  if (i < 131072){ Wb_bf[i] = f2bf(Wih_b[i]); return; }
  i -= 131072;
  if (i < 393216){ Wg_bf[i] = f2bf(Wih_g[i]); return; }
  i -= 393216;
  if (i < 32768){ Wgen_bf[i] = f2bf(Wgen[i]); return; }
  i -= 32768;
  if (i < 65536){ Whf_h[i] = (f16_t)Whh_f[i]; return; }
  i -= 65536;
  if (i < 65536){ Whb_h[i] = (f16_t)Whh_b[i]; return; }
  i -= 65536;
  if (i < 196608){ Whg_h[i] = (f16_t)Whh_g[i]; return; }
  i -= 196608;
  emb_bf[i] = f2bf(emb[i]);
}

// ---------------- K1: attention pooling via MFMA + fused row-sum + fused weight-prep -------
// Blocks 0..255: pool (sample b, c-half ch). Blocks 256..256+NPREP-1: grid-stride weight prep.
__global__ __launch_bounds__(256) void k_pool_mfma(const float* __restrict__ feat, const float* __restrict__ A,
    float* __restrict__ S, ushort_t* __restrict__ Cbf,
    const float* __restrict__ Wih_f, const float* __restrict__ Wih_b,
    const float* __restrict__ Wih_g, const float* __restrict__ Wgen,
    const float* __restrict__ Whh_f, const float* __restrict__ Whh_b,
    const float* __restrict__ Whh_g, const float* __restrict__ emb,
    ushort_t* __restrict__ Wf_bf, ushort_t* __restrict__ Wb_bf,
    ushort_t* __restrict__ Wg_bf, ushort_t* __restrict__ Wgen_bf,
    f16_t* __restrict__ Whf_h, f16_t* __restrict__ Whb_h, f16_t* __restrict__ Whg_h,
    ushort_t* __restrict__ emb_bf){
  __shared__ ushort_t As_[64*40];
  __shared__ ushort_t Fs_[128*40];
  __shared__ float sinvs[64];
  __shared__ float psum[512];
  int tid = threadIdx.x;
  if (blockIdx.x >= 256){
    int base = (blockIdx.x - 256)*256 + tid;
    for (int i = base; i < 1048576; i += NPREP*256)
      prep_elem(i, Wih_f, Wih_b, Wih_g, Wgen, Whh_f, Whh_b, Whh_g, emb,
                Wf_bf, Wb_bf, Wg_bf, Wgen_bf, Whf_h, Whb_h, Whg_h, emb_bf);
    return;
  }
  int b = blockIdx.x >> 1, ch = blockIdx.x & 1, c0 = ch*128;
  int wave = tid>>6, lane = tid&63;
  f32x4 acc[4][2] = {};
  int lr = lane & 15, lk = (lane>>4)*8;
  float sA0 = 0.f, sA1 = 0.f;
  for (int k0=0;k0<NHW;k0+=32){
    __syncthreads();
    #pragma unroll
    for (int i=0;i<2;i++){
      int c = tid + i*256, r = c>>3, kq = c&7;
      float4 v = *(const float4*)(A + ((size_t)(b*64+r))*NHW + k0 + kq*4);
      float sv = v.x+v.y+v.z+v.w;
      if (i==0) sA0 += sv; else sA1 += sv;
      bf16x4 p; p[0]=(short)f2bf(v.x); p[1]=(short)f2bf(v.y); p[2]=(short)f2bf(v.z); p[3]=(short)f2bf(v.w);
      *(bf16x4*)&As_[r*40 + kq*4] = p;
    }
    #pragma unroll
    for (int i=0;i<4;i++){
      int c = tid + i*256, r = c>>3, kq = c&7;
      float4 v = *(const float4*)(feat + ((size_t)(b*256+c0+r))*NHW + k0 + kq*4);
      bf16x4 p; p[0]=(short)f2bf(v.x); p[1]=(short)f2bf(v.y); p[2]=(short)f2bf(v.z); p[3]=(short)f2bf(v.w);
      *(bf16x4*)&Fs_[r*40 + kq*4] = p;
    }
    __syncthreads();
    bf16x8 af[4], bg[2];
    #pragma unroll
    for (int m=0;m<4;m++) af[m] = *(const bf16x8*)&As_[(m*16 + lr)*40 + lk];
    #pragma unroll
    for (int n=0;n<2;n++) bg[n] = *(const bf16x8*)&Fs_[(wave*32 + n*16 + lr)*40 + lk];
    #pragma unroll
    for (int m=0;m<4;m++)
      #pragma unroll
      for (int n=0;n<2;n++)
        acc[m][n] = __builtin_amdgcn_mfma_f32_16x16x32_bf16(af[m], bg[n], acc[m][n], 0, 0, 0);
  }
  psum[tid] = sA0;
  psum[tid+256] = sA1;
  __syncthreads();
  if (tid < 64){
    float s = 0.f;
    #pragma unroll
    for (int j=0;j<8;j++) s += psum[tid*8 + j];
    sinvs[tid] = 1.f / s;
    if (ch == 0) S[b*64 + tid] = s;
  }
  __syncthreads();
  #pragma unroll
  for (int m=0;m<4;m++)
    #pragma unroll
    for (int n=0;n<2;n++)
      #pragma unroll
      for (int j=0;j<4;j++){
        int t = m*16 + (lane>>4)*4 + j;
        int c = c0 + wave*32 + n*16 + lr;
        Cbf[((size_t)t*NBATCH + b)*NCH + c] = f2bf(acc[m][n][j] * sinvs[t]);
      }
}

// ---------------- merged F+B LSTM-projection GEMM: blocks 0-3 F, 4-7 B ----------------
__global__ __launch_bounds__(256) void k_gemm_fb(const ushort_t* __restrict__ X,
    const ushort_t* __restrict__ Wf, const ushort_t* __restrict__ Wb,
    const float* __restrict__ bihf, const float* __restrict__ bhhf,
    const float* __restrict__ bihb, const float* __restrict__ bhhb,
    float* __restrict__ outF, float* __restrict__ outB){
  const int N = 512, K = 256;
  __shared__ ushort_t Xs[128*40];
  __shared__ ushort_t Ws[128*40];
  bool isB = blockIdx.x >= 4;
  const ushort_t* W = isB ? Wb : Wf;
  const float* ba = isB ? bihb : bihf;
  const float* bb = isB ? bhhb : bhhf;
  float* out = isB ? outB : outF;
  int n0 = (blockIdx.x & 3)*128, m0 = blockIdx.y*128;
  int tid = threadIdx.x, wave = tid>>6, lane = tid&63;
  int wr = wave>>1, wc = wave&1;
  int lr = lane & 15, lk = (lane>>4)*8;
  f32x4 acc[4][4] = {};
  for (int k0=0;k0<K;k0+=32){
    __syncthreads();
    #pragma unroll
    for (int i=0;i<2;i++){
      int c = tid + i*256, r = c>>2, kb = c&3;
      *(bf16x8*)&Xs[r*40 + kb*8] = *(const bf16x8*)(X + (size_t)(m0+r)*K + k0 + kb*8);
      *(bf16x8*)&Ws[r*40 + kb*8] = *(const bf16x8*)(W + (size_t)(n0+r)*K + k0 + kb*8);
    }
    __syncthreads();
    bf16x8 af[4], bg[4];
    #pragma unroll
    for (int m=0;m<4;m++) af[m] = *(const bf16x8*)&Xs[(wr*64 + m*16 + lr)*40 + lk];
    #pragma unroll
    for (int n=0;n<4;n++) bg[n] = *(const bf16x8*)&Ws[(wc*64 + n*16 + lr)*40 + lk];
    #pragma unroll
    for (int m=0;m<4;m++)
      #pragma unroll
      for (int n=0;n<4;n++)
        acc[m][n] = __builtin_amdgcn_mfma_f32_16x16x32_bf16(af[m], bg[n], acc[m][n], 0, 0, 0);
  }
  float bsv[4];
  #pragma unroll
  for (int n=0;n<4;n++){
    int col = n0 + wc*64 + n*16 + lr;
    bsv[n] = ba[col] + bb[col];
  }
  #pragma unroll
  for (int m=0;m<4;m++)
    #pragma unroll
    for (int n=0;n<4;n++)
      #pragma unroll
      for (int j=0;j<4;j++){
        int row = m0 + wr*64 + m*16 + (lane>>4)*4 + j;
        int col = n0 + wc*64 + n*16 + lr;
        out[(size_t)row*N + col] = acc[m][n][j] + bsv[n];
      }
}

// ---------------- gx GEMM with fused xs-gather ----------------
__global__ __launch_bounds__(256) void k_gemm_gx(const ushort_t* __restrict__ Clbf,
    const ushort_t* __restrict__ emb_bf, const int* __restrict__ text,
    const ushort_t* __restrict__ W, const float* __restrict__ ba,
    float* __restrict__ out){
  __shared__ ushort_t Xs[128*40];
  __shared__ ushort_t Ws[128*40];
  __shared__ int clsL[128];
  const int N = 768, K = 512;
  int n0 = blockIdx.x*128, m0 = blockIdx.y*128;
  int tid = threadIdx.x, wave = tid>>6, lane = tid&63;
  int wr = wave>>1, wc = wave&1;
  int lr = lane & 15, lk = (lane>>4)*8;
  if (tid < 128){
    int m = m0 + tid, t = m>>7, b = m&127;
    clsL[tid] = (t==0) ? 0 : text[b*64 + (t-1)];
  }
  f32x4 acc[4][4] = {};
  __syncthreads();
  for (int k0=0;k0<K;k0+=32){
    __syncthreads();
    #pragma unroll
    for (int i=0;i<2;i++){
      int c = tid + i*256, r = c>>2, kb = c&3;
      int col = k0 + kb*8;
      bf16x8 xv;
      if (col < 256) xv = *(const bf16x8*)(Clbf + (size_t)(m0+r)*NCH + col);
      else           xv = *(const bf16x8*)(emb_bf + (size_t)clsL[r]*NCH + (col-256));
      *(bf16x8*)&Xs[r*40 + kb*8] = xv;
      *(bf16x8*)&Ws[r*40 + kb*8] = *(const bf16x8*)(W + (size_t)(n0+r)*K + k0 + kb*8);
    }
    __syncthreads();
    bf16x8 af[4], bg[4];
    #pragma unroll
    for (int m=0;m<4;m++) af[m] = *(const bf16x8*)&Xs[(wr*64 + m*16 + lr)*40 + lk];
    #pragma unroll
    for (int n=0;n<4;n++) bg[n] = *(const bf16x8*)&Ws[(wc*64 + n*16 + lr)*40 + lk];
    #pragma unroll
    for (int m=0;m<4;m++)
      #pragma unroll
      for (int n=0;n<4;n++)
        acc[m][n] = __builtin_amdgcn_mfma_f32_16x16x32_bf16(af[m], bg[n], acc[m][n], 0, 0, 0);
  }
  float bsv[4];
  #pragma unroll
  for (int n=0;n<4;n++) bsv[n] = ba[n0 + wc*64 + n*16 + lr];
  #pragma unroll
  for (int m=0;m<4;m++)
    #pragma unroll
    for (int n=0;n<4;n++)
      #pragma unroll
      for (int j=0;j<4;j++){
        int row = m0 + wr*64 + m*16 + (lane>>4)*4 + j;
        int col = n0 + wc*64 + n*16 + lr;
        out[(size_t)row*N + col] = acc[m][n][j] + bsv[n];
      }
}

// ---------------- K3: BiLSTM scan, dot2+readlane, W resident in LDS ----------------
__global__ __launch_bounds__(512) void k_lstm_ldsT(const float* __restrict__ Gf, const float* __restrict__ Gb,
    const f16_t* __restrict__ Whf, const f16_t* __restrict__ Whb, ushort_t* __restrict__ Clbf){
  extern __shared__ char smem[];
  int2*  Wt2   = (int2*)smem;                       // 131072 B
  float* h32   = (float*)(smem + 131072);           // 128 f32
  float* gates = (float*)(smem + 131072 + 512);     // 512 f32
  int b = blockIdx.x & 127, dir = blockIdx.x >> 7;
  const f16_t* W = dir ? Whb : Whf;                 // [512][128]
  const float* G = dir ? Gb : Gf;                   // [t][128][512] (biases folded)
  int g = threadIdx.x, lane = g & 63;
  {
    const int2* wr = (const int2*)(W + (size_t)g*128);
    #pragma unroll
    for (int p2=0;p2<32;p2++) Wt2[p2*512 + g] = wr[p2];
  }
  if (g < 128) h32[g] = 0.f;
  float c = 0.f;
  __syncthreads();
  #pragma unroll 1
  for (int t=0;t<NTIME;t++){
    int tt = dir ? (NTIME-1-t) : t;
    float gv = G[((size_t)tt*NBATCH + b)*512 + g];
    float2 hp2 = *(const float2*)(h32 + 2*lane);
    int hpk = __builtin_bit_cast(int, pack2(hp2.x, hp2.y));
    float a0=0.f, a1=0.f, a2=0.f, a3=0.f;
    #pragma unroll
    for (int p2=0;p2<32;p2+=2){
      int2 w0 = Wt2[p2*512 + g];
      int2 w1 = Wt2[(p2+1)*512 + g];
      int h0 = __builtin_amdgcn_readlane(hpk, 2*p2);
      int h1 = __builtin_amdgcn_readlane(hpk, 2*p2+1);
      int h2 = __builtin_amdgcn_readlane(hpk, 2*p2+2);
      int h3 = __builtin_amdgcn_readlane(hpk, 2*p2+3);
      a0 = dot2acc(BCH(w0.x), BCH(h0), a0);
      a1 = dot2acc(BCH(w0.y), BCH(h1), a1);
      a2 = dot2acc(BCH(w1.x), BCH(h2), a2);
      a3 = dot2acc(BCH(w1.y), BCH(h3), a3);
    }
    gates[g] = gv + a0+a1+a2+a3;
    __syncthreads();
    if (g < 128){
      float gi=gates[g], gf=gates[128+g], gg=gates[256+g], go=gates[384+g];
      c = sig_(gf)*c + sig_(gi)*tanh_(gg);
      float h = sig_(go)*tanh_(c);
      h32[g] = h;
      Clbf[((size_t)tt*NBATCH + b)*NCH + dir*128 + g] = f2bf(h);
    }
    __syncthreads();
  }
}

// ---------------- K5: GRU scan (R17-proven) + fused packed-attn blocks ----------------
__global__ __launch_bounds__(512, 1) void k_gru(const float* __restrict__ gx,
    const float* __restrict__ Whh_g, const float* __restrict__ bhh_g, ushort_t* __restrict__ hsbf,
    const float* __restrict__ A, const float* __restrict__ S,
    const int* __restrict__ pack_b, const int* __restrict__ pack_t,
    float* __restrict__ outA, int L){
  int b = blockIdx.x, t0 = threadIdx.x, lane = t0 & 63, w = t0 >> 6;
  if (b >= NBATCH){
    int ab = b - NBATCH;
    int half = t0 >> 8, q = t0 & 255;
    for (int r0 = ab*2; r0 < L; r0 += NATTN*2){
      int r = r0 + half;
      if (r < L){
        int bb = pack_b[r], tt = pack_t[r];
        float is = 1.f / S[bb*64 + tt];
        float4 v = ((const float4*)(A + ((size_t)(bb*64+tt))*NHW))[q];
        v.x*=is; v.y*=is; v.z*=is; v.w*=is;
        ((float4*)(outA + (size_t)r*NHW))[q] = v;
      }
    }
    return;
  }
  half2_t wpA[64], wpB[64], wpC[64];
  int pidxA, pidxB, pidxC;
  int hfbA, hfbB, hfbC;

#define LOADW(WP, PIDX, HFB, S_) do { \
    int c = w*3 + (S_); \
    int hf = (c >= 12) ? 1 : 0; \
    int row = (c - hf*12)*64 + lane; \
    PIDX = hf*768 + row; \
    HFB  = __builtin_amdgcn_readfirstlane(hf*32); \
    const float4* wr = (const float4*)(Whh_g + (size_t)row*256 + hf*128); \
    _Pragma("unroll") \
    for (int j=0;j<32;j++){ \
      float4 v = wr[j]; \
      WP[2*j]   = pack2(v.x, v.y); \
      WP[2*j+1] = pack2(v.z, v.w); \
    } \
  } while(0)

  LOADW(wpA, pidxA, hfbA, 0);
  LOADW(wpB, pidxB, hfbB, 1);
  LOADW(wpC, pidxC, hfbC, 2);
#undef LOADW

  __shared__ float h32[256];
  __shared__ float partLds[1536];
  __shared__ float bhL[768];
  if (t0 < 256) h32[t0] = 0.f;
  bhL[t0] = bhh_g[t0];
  if (t0 < 256) bhL[512+t0] = bhh_g[512+t0];
  float hprev = 0.f;
  __syncthreads();
  #pragma unroll 1
  for (int t=0;t<NTIME;t++){
    float gxr=0.f, gxz=0.f, gxn=0.f;
    if (t0 < 256){
      const float* gxp = gx + ((size_t)t*NBATCH + b)*768;
      gxr = gxp[t0]; gxz = gxp[256+t0]; gxn = gxp[512+t0];
    }
    float4 hq = *(const float4*)(h32 + 4*lane);
    int hpk0 = __builtin_bit_cast(int, pack2(hq.x, hq.y));
    int hpk1 = __builtin_bit_cast(int, pack2(hq.z, hq.w));

#define DOTASK(WP, PIDX, HFB) do { \
    float a0=0.f, a1=0.f, a2=0.f, a3=0.f; \
    _Pragma("unroll") \
    for (int jj=0;jj<64;jj+=2){ \
      int hv0 = __builtin_amdgcn_readlane(hpk0, HFB + (jj>>1)); \
      int hv1 = __builtin_amdgcn_readlane(hpk1, HFB + (jj>>1)); \
      if ((jj>>1)&1){ \
        a2 = dot2acc(WP[jj],   __builtin_bit_cast(half2_t, hv0), a2); \
        a3 = dot2acc(WP[jj+1], __builtin_bit_cast(half2_t, hv1), a3); \
      } else { \
        a0 = dot2acc(WP[jj],   __builtin_bit_cast(half2_t, hv0), a0); \
        a1 = dot2acc(WP[jj+1], __builtin_bit_cast(half2_t, hv1), a1); \
      } \
    } \
    partLds[PIDX] = a0+a1+a2+a3; \
  } while(0)

    DOTASK(wpA, pidxA, hfbA);
    DOTASK(wpB, pidxB, hfbB);
    DOTASK(wpC, pidxC, hfbC);
#undef DOTASK

    __syncthreads();
    if (t0 < 256){
      float rh = bhL[t0]     + partLds[t0]     + partLds[768+t0];
      float zh = bhL[256+t0] + partLds[256+t0] + partLds[1024+t0];
      float nh = bhL[512+t0] + partLds[512+t0] + partLds[1280+t0];
      float r = sig_(gxr + rh);
      float z = sig_(gxz + zh);
      float n = tanh_(gxn + r*nh);
      float h = (1.f-z)*n + z*hprev;
      hprev = h;
      h32[t0] = h;
      hsbf[((size_t)t*NBATCH + b)*NCH + t0] = f2bf(h);
    }
    __syncthreads();
  }
}

// ---------------- K6: logits via MFMA with row gather ----------------
__global__ __launch_bounds__(256) void k_logits_mfma(const ushort_t* __restrict__ hsbf,
    const int* __restrict__ pack_t, const int* __restrict__ pack_b,
    const ushort_t* __restrict__ Wbf, const float* __restrict__ bias,
    float* __restrict__ out, int L){
  __shared__ ushort_t Xs[64*40];
  __shared__ ushort_t Ws[128*40];
  __shared__ int rrow[64];
  int m0 = blockIdx.x*64;
  int tid = threadIdx.x, wave = tid>>6, lane = tid&63;
  int lr = lane & 15, lk = (lane>>4)*8;
  if (tid < 64){
    int m = m0 + tid;
    int pt = (m<L) ? pack_t[m] : 0;
    int pb = (m<L) ? pack_b[m] : 0;
    rrow[tid] = pt*NBATCH + pb;
  }
  f32x4 acc[4][2] = {};
  for (int k0=0;k0<NCH;k0+=32){
    __syncthreads();
    {
      int r = tid>>2, kb = tid&3;
      *(bf16x8*)&Xs[r*40 + kb*8] = *(const bf16x8*)(hsbf + (size_t)rrow[r]*NCH + k0 + kb*8);
    }
    #pragma unroll
    for (int i=0;i<2;i++){
      int c = tid + i*256, r = c>>2, kb = c&3;
      *(bf16x8*)&Ws[r*40 + kb*8] = *(const bf16x8*)(Wbf + (size_t)r*NCH + k0 + kb*8);
    }
    __syncthreads();
    bf16x8 af[4], bg[2];
    #pragma unroll
    for (int m=0;m<4;m++) af[m] = *(const bf16x8*)&Xs[(m*16 + lr)*40 + lk];
    #pragma unroll
    for (int n=0;n<2;n++) bg[n] = *(const bf16x8*)&Ws[(wave*32 + n*16 + lr)*40 + lk];
    #pragma unroll
    for (int m=0;m<4;m++)
      #pragma unroll
      for (int n=0;n<2;n++)
        acc[m][n] = __builtin_amdgcn_mfma_f32_16x16x32_bf16(af[m], bg[n], acc[m][n], 0, 0, 0);
  }
  #pragma unroll
  for (int m=0;m<4;m++)
    #pragma unroll
    for (int n=0;n<2;n++)
      #pragma unroll
      for (int j=0;j<4;j++){
        int row = m0 + m*16 + (lane>>4)*4 + j;
        int col = wave*32 + n*16 + lr;
        if (row < L) out[(size_t)row*NCLS + col] = acc[m][n][j] + bias[col];
      }
}

extern "C" void kernel_launch(void* const* d_in, const int* in_sizes, int n_in,
                              void* d_out, int out_size, void* d_ws, size_t ws_size,
                              hipStream_t stream) {
  const float* feature = (const float*)d_in[0];
  const float* A       = (const float*)d_in[1];
  const int*   text    = (const int*)d_in[2];
  const int*   pack_b  = (const int*)d_in[4];
  const int*   pack_t  = (const int*)d_in[5];
  const float* emb     = (const float*)d_in[6];
  const float* Wih_f   = (const float*)d_in[7];
  const float* Whh_f   = (const float*)d_in[8];
  const float* bih_f   = (const float*)d_in[9];
  const float* bhh_f   = (const float*)d_in[10];
  const float* Wih_b   = (const float*)d_in[11];
  const float* Whh_b   = (const float*)d_in[12];
  const float* bih_b   = (const float*)d_in[13];
  const float* bhh_b   = (const float*)d_in[14];
  const float* Wih_g   = (const float*)d_in[15];
  const float* Whh_g   = (const float*)d_in[16];
  const float* bih_g   = (const float*)d_in[17];
  const float* bhh_g   = (const float*)d_in[18];
  const float* Wgen    = (const float*)d_in[19];
  const float* bgen    = (const float*)d_in[20];
  int L = in_sizes[4];

  char* ws = (char*)d_ws;
  const size_t KB = 1024, MB = 1u<<20;
  float*    S       = (float*)(ws + 0);                    // 32 KB
  ushort_t* Wf_bf   = (ushort_t*)(ws + 1*MB);              // 256 KB
  ushort_t* Wb_bf   = (ushort_t*)(ws + 1*MB + 256*KB);     // 256 KB
  ushort_t* Wg_bf   = (ushort_t*)(ws + 1*MB + 512*KB);     // 768 KB
  ushort_t* Wgen_bf = (ushort_t*)(ws + 2*MB + 256*KB);     // 64 KB
  f16_t*    Whf_h   = (f16_t*)(ws + 2*MB + 512*KB);        // 128 KB
  f16_t*    Whb_h   = (f16_t*)(ws + 2*MB + 640*KB);        // 128 KB
  f16_t*    Whg_h   = (f16_t*)(ws + 2*MB + 768*KB);        // 384 KB
  ushort_t* emb_bf  = (ushort_t*)(ws + 3*MB + 256*KB);     // 64 KB
  ushort_t* Cbf     = (ushort_t*)(ws + 4*MB);              // 4 MB
  ushort_t* Clbf    = (ushort_t*)(ws + 8*MB);              // 4 MB
  ushort_t* hsbf    = (ushort_t*)(ws + 12*MB);             // 4 MB
  float*    Gf      = (float*)(ws + 16*MB);                // 16 MB (dead after k_lstm)
  float*    Gb      = (float*)(ws + 32*MB);                // 16 MB (dead after k_lstm)
  float*    gx      = (float*)(ws + 24*MB);                // 25.2 MB, aliases Gb+ (after lstm)

  float* out_res   = (float*)d_out;
  float* out_attns = out_res + (size_t)L*NCLS;

  const int LSTM_SMEM = 131072 + 512 + 2048;               // 133,632 B
  (void)hipFuncSetAttribute((const void*)k_lstm_ldsT,
                            hipFuncAttributeMaxDynamicSharedMemorySize, LSTM_SMEM);

  k_pool_mfma<<<256 + NPREP, 256, 0, stream>>>(feature, A, S, Cbf,
      Wih_f, Wih_b, Wih_g, Wgen, Whh_f, Whh_b, Whh_g, emb,
      Wf_bf, Wb_bf, Wg_bf, Wgen_bf, Whf_h, Whb_h, Whg_h, emb_bf);
  k_gemm_fb<<<dim3(8,64), 256, 0, stream>>>(Cbf, Wf_bf, Wb_bf,
      bih_f, bhh_f, bih_b, bhh_b, Gf, Gb);
  k_lstm_ldsT<<<256, 512, LSTM_SMEM, stream>>>(Gf, Gb, Whf_h, Whb_h, Clbf);
  k_gemm_gx<<<dim3(6,64), 256, 0, stream>>>(Clbf, emb_bf, text, Wg_bf, bih_g, gx);
  k_gru<<<NBATCH + NATTN, 512, 0, stream>>>(gx, Whh_g, bhh_g, hsbf,
                                            A, S, pack_b, pack_t, out_attns, L);
  k_logits_mfma<<<(L+63)/64, 256, 0, stream>>>(hsbf, pack_t, pack_b, Wgen_bf, bgen, out_res, L);
}